// Round 1
// baseline (125.780 us; speedup 1.0000x reference)
//
#include <hip/hip_runtime.h>

#define K 8

typedef float f32x4 __attribute__((ext_vector_type(4)));
typedef int   i32x4 __attribute__((ext_vector_type(4)));

// ---------------------------------------------------------------------------
// Kernel 1: per-POINT Phong shading -> float4 color table in workspace.
// Shading depends only on (point, normal, global constants), never the pixel,
// so evaluate it P=100K times instead of N*H*W*K = 4.2M times.
// ---------------------------------------------------------------------------
__global__ __launch_bounds__(256) void shade_points_kernel(
    const float* __restrict__ points,
    const float* __restrict__ normals,
    const float* __restrict__ light_location,
    const float* __restrict__ light_ambient,
    const float* __restrict__ light_diffuse,
    const float* __restrict__ light_specular,
    const float* __restrict__ mat_ambient,
    const float* __restrict__ mat_diffuse,
    const float* __restrict__ mat_specular,
    const float* __restrict__ camera_position,
    const int*   __restrict__ shininess_p,
    f32x4*       __restrict__ colors,
    int P)
{
    const int i = blockIdx.x * blockDim.x + threadIdx.x;
    if (i >= P) return;

    const float Lx = light_location[0], Ly = light_location[1], Lz = light_location[2];
    const float Cx = camera_position[0], Cy = camera_position[1], Cz = camera_position[2];
    const float amb0 = light_ambient[0] * mat_ambient[0];
    const float amb1 = light_ambient[1] * mat_ambient[1];
    const float amb2 = light_ambient[2] * mat_ambient[2];
    const float dif0 = light_diffuse[0] * mat_diffuse[0];
    const float dif1 = light_diffuse[1] * mat_diffuse[1];
    const float dif2 = light_diffuse[2] * mat_diffuse[2];
    const float spc0 = light_specular[0] * mat_specular[0];
    const float spc1 = light_specular[1] * mat_specular[1];
    const float spc2 = light_specular[2] * mat_specular[2];
    const int   shin = shininess_p[0];

    const size_t b = (size_t)i * 3;
    const float px = points[b],  py = points[b + 1],  pz = points[b + 2];
    const float nx = normals[b], ny = normals[b + 1], nz = normals[b + 2];

    // identical math/order to the previously-verified per-pixel version
    float lx = Lx - px, ly = Ly - py, lz = Lz - pz;
    float ll = lx * lx + ly * ly + lz * lz;
    float li = (ll > 1e-12f) ? rsqrtf(ll) : 1e6f;
    lx *= li; ly *= li; lz *= li;

    const float cosv = nx * lx + ny * ly + nz * lz;

    float vx = Cx - px, vy = Cy - py, vz = Cz - pz;
    float vv = vx * vx + vy * vy + vz * vz;
    float vi = (vv > 1e-12f) ? rsqrtf(vv) : 1e6f;
    vx *= vi; vy *= vi; vz *= vi;

    const float c2 = 2.0f * cosv;
    const float rx = c2 * nx - lx;
    const float ry = c2 * ny - ly;
    const float rz = c2 * nz - lz;

    float alpha = fmaxf(vx * rx + vy * ry + vz * rz, 0.0f);
    if (!(cosv > 0.0f)) alpha = 0.0f;

    float sp = 1.0f, bb = alpha;
    int e = shin;
    while (e > 0) {
        if (e & 1) sp *= bb;
        bb *= bb;
        e >>= 1;
    }

    const float rc = fmaxf(cosv, 0.0f);
    f32x4 c;
    c.x = amb0 + dif0 * rc + spc0 * sp;
    c.y = amb1 + dif1 * rc + spc1 * sp;
    c.z = amb2 + dif2 * rc + spc2 * sp;
    c.w = 0.0f;
    colors[i] = c;
}

// ---------------------------------------------------------------------------
// Kernel 2: pure gather-and-blend. 1x float4 gather per (pixel,k) from the
// 1.6 MB L2-resident color table; streaming idx/dists/out non-temporal so
// they don't evict the table.
// ---------------------------------------------------------------------------
__global__ __launch_bounds__(256) void composite_kernel(
    const int*   __restrict__ idx,
    const float* __restrict__ dists,
    const f32x4* __restrict__ colors,
    float*       __restrict__ out,
    int n_pix)
{
    const int p = blockIdx.x * blockDim.x + threadIdx.x;
    if (p >= n_pix) return;

    const i32x4* idxv = reinterpret_cast<const i32x4*>(idx + (size_t)p * K);
    const f32x4* dstv = reinterpret_cast<const f32x4*>(dists + (size_t)p * K);
    const i32x4 i0 = __builtin_nontemporal_load(idxv);
    const i32x4 i1 = __builtin_nontemporal_load(idxv + 1);
    const f32x4 d0 = __builtin_nontemporal_load(dstv);
    const f32x4 d1 = __builtin_nontemporal_load(dstv + 1);

    const int   ik[K] = {i0.x, i0.y, i0.z, i0.w, i1.x, i1.y, i1.z, i1.w};
    const float dk[K] = {d0.x, d0.y, d0.z, d0.w, d1.x, d1.y, d1.z, d1.w};

    // issue all 8 gathers first for max memory-level parallelism
    f32x4 ck[K];
#pragma unroll
    for (int k = 0; k < K; ++k) {
        const int ii = (ik[k] < 0) ? 0 : ik[k];
        ck[k] = colors[ii];
    }

    float wsum = 0.f;
    float acc0 = 0.f, acc1 = 0.f, acc2 = 0.f;
#pragma unroll
    for (int k = 0; k < K; ++k) {
        const float d = dk[k];
        const float m = (d != -1.0f) ? d : 0.0f;
        wsum += fabsf(m);
        acc0 += m * ck[k].x;
        acc1 += m * ck[k].y;
        acc2 += m * ck[k].z;
    }
    const float winv = 1.0f / fmaxf(wsum, 1e-12f);

    float* o = out + (size_t)p * 3;
    __builtin_nontemporal_store(acc0 * winv, o);
    __builtin_nontemporal_store(acc1 * winv, o + 1);
    __builtin_nontemporal_store(acc2 * winv, o + 2);
}

// ---------------------------------------------------------------------------
// Fallback (workspace too small): previously-verified fused per-pixel kernel.
// ---------------------------------------------------------------------------
__global__ __launch_bounds__(256) void shading_compositor_fallback(
    const int*    __restrict__ idx,
    const float*  __restrict__ dists,
    const float*  __restrict__ points,
    const float*  __restrict__ normals,
    const float*  __restrict__ light_location,
    const float*  __restrict__ light_ambient,
    const float*  __restrict__ light_diffuse,
    const float*  __restrict__ light_specular,
    const float*  __restrict__ mat_ambient,
    const float*  __restrict__ mat_diffuse,
    const float*  __restrict__ mat_specular,
    const float*  __restrict__ camera_position,
    const int*    __restrict__ shininess_p,
    float*        __restrict__ out,
    int n_pix)
{
    const int p = blockIdx.x * blockDim.x + threadIdx.x;
    if (p >= n_pix) return;

    const float Lx = light_location[0], Ly = light_location[1], Lz = light_location[2];
    const float Cx = camera_position[0], Cy = camera_position[1], Cz = camera_position[2];
    const float amb0 = light_ambient[0] * mat_ambient[0];
    const float amb1 = light_ambient[1] * mat_ambient[1];
    const float amb2 = light_ambient[2] * mat_ambient[2];
    const float dif0 = light_diffuse[0] * mat_diffuse[0];
    const float dif1 = light_diffuse[1] * mat_diffuse[1];
    const float dif2 = light_diffuse[2] * mat_diffuse[2];
    const float spc0 = light_specular[0] * mat_specular[0];
    const float spc1 = light_specular[1] * mat_specular[1];
    const float spc2 = light_specular[2] * mat_specular[2];
    const int   shin = shininess_p[0];

    const int4*   idxv = reinterpret_cast<const int4*>(idx   + (size_t)p * K);
    const float4* dstv = reinterpret_cast<const float4*>(dists + (size_t)p * K);
    int4   i0 = idxv[0], i1 = idxv[1];
    float4 d0 = dstv[0], d1 = dstv[1];

    int   ik[K] = {i0.x, i0.y, i0.z, i0.w, i1.x, i1.y, i1.z, i1.w};
    float dk[K] = {d0.x, d0.y, d0.z, d0.w, d1.x, d1.y, d1.z, d1.w};

    float w[K];
    float wsum = 0.f;
#pragma unroll
    for (int k = 0; k < K; ++k) {
        float d = dk[k];
        float m = (d != -1.0f) ? d : 0.0f;
        w[k] = m;
        wsum += fabsf(m);
    }
    const float winv = 1.0f / fmaxf(wsum, 1e-12f);

    float acc0 = 0.f, acc1 = 0.f, acc2 = 0.f;

#pragma unroll
    for (int k = 0; k < K; ++k) {
        const int ii = (ik[k] < 0) ? 0 : ik[k];
        const size_t base = (size_t)ii * 3;
        const float px = points[base],  py = points[base + 1],  pz = points[base + 2];
        const float nx = normals[base], ny = normals[base + 1], nz = normals[base + 2];

        float lx = Lx - px, ly = Ly - py, lz = Lz - pz;
        float ll = lx * lx + ly * ly + lz * lz;
        float li = (ll > 1e-12f) ? rsqrtf(ll) : 1e6f;
        lx *= li; ly *= li; lz *= li;

        const float cosv = nx * lx + ny * ly + nz * lz;

        float vx = Cx - px, vy = Cy - py, vz = Cz - pz;
        float vv = vx * vx + vy * vy + vz * vz;
        float vi = (vv > 1e-12f) ? rsqrtf(vv) : 1e6f;
        vx *= vi; vy *= vi; vz *= vi;

        const float c2 = 2.0f * cosv;
        const float rx = c2 * nx - lx;
        const float ry = c2 * ny - ly;
        const float rz = c2 * nz - lz;

        float alpha = fmaxf(vx * rx + vy * ry + vz * rz, 0.0f);
        if (!(cosv > 0.0f)) alpha = 0.0f;

        float sp = 1.0f, bb = alpha;
        int e = shin;
        while (e > 0) {
            if (e & 1) sp *= bb;
            bb *= bb;
            e >>= 1;
        }

        const float rc = fmaxf(cosv, 0.0f);
        const float wk = w[k];
        acc0 += wk * (amb0 + dif0 * rc + spc0 * sp);
        acc1 += wk * (amb1 + dif1 * rc + spc1 * sp);
        acc2 += wk * (amb2 + dif2 * rc + spc2 * sp);
    }

    float* o = out + (size_t)p * 3;
    o[0] = acc0 * winv;
    o[1] = acc1 * winv;
    o[2] = acc2 * winv;
}

extern "C" void kernel_launch(void* const* d_in, const int* in_sizes, int n_in,
                              void* d_out, int out_size, void* d_ws, size_t ws_size,
                              hipStream_t stream) {
    const int*   idx             = (const int*)d_in[0];
    const float* dists           = (const float*)d_in[1];
    const float* points          = (const float*)d_in[2];
    const float* normals         = (const float*)d_in[3];
    const float* light_location  = (const float*)d_in[4];
    const float* light_ambient   = (const float*)d_in[5];
    const float* light_diffuse   = (const float*)d_in[6];
    const float* light_specular  = (const float*)d_in[7];
    const float* mat_ambient     = (const float*)d_in[8];
    const float* mat_diffuse     = (const float*)d_in[9];
    const float* mat_specular    = (const float*)d_in[10];
    const float* camera_position = (const float*)d_in[11];
    const int*   shininess       = (const int*)d_in[12];
    float*       out             = (float*)d_out;

    const int n_pix = in_sizes[0] / K;       // N*H*W
    const int P     = in_sizes[2] / 3;       // number of points

    const int block = 256;
    const int grid  = (n_pix + block - 1) / block;

    const size_t need = (size_t)P * sizeof(f32x4);
    if (ws_size >= need) {
        f32x4* colors = (f32x4*)d_ws;
        shade_points_kernel<<<(P + block - 1) / block, block, 0, stream>>>(
            points, normals, light_location, light_ambient, light_diffuse,
            light_specular, mat_ambient, mat_diffuse, mat_specular,
            camera_position, shininess, colors, P);
        composite_kernel<<<grid, block, 0, stream>>>(idx, dists, colors, out, n_pix);
    } else {
        shading_compositor_fallback<<<grid, block, 0, stream>>>(
            idx, dists, points, normals, light_location, light_ambient,
            light_diffuse, light_specular, mat_ambient, mat_diffuse,
            mat_specular, camera_position, shininess, out, n_pix);
    }
}

// Round 2
// 124.117 us; speedup vs baseline: 1.0134x; 1.0134x over previous
//
#include <hip/hip_runtime.h>

#define K 8

typedef float f32x4 __attribute__((ext_vector_type(4)));
typedef float f32x2 __attribute__((ext_vector_type(2)));
typedef int   i32x4 __attribute__((ext_vector_type(4)));

struct F3 { float x, y, z; };   // 12B packed color record

// ---------------------------------------------------------------------------
// Kernel 1: per-POINT Phong shading -> 12B f32x3 color table in workspace.
// P=100K evaluations instead of N*H*W*K=4.2M. Table = 1.2 MB (L2-resident).
// ---------------------------------------------------------------------------
__global__ __launch_bounds__(256) void shade_points_kernel(
    const float* __restrict__ points,
    const float* __restrict__ normals,
    const float* __restrict__ light_location,
    const float* __restrict__ light_ambient,
    const float* __restrict__ light_diffuse,
    const float* __restrict__ light_specular,
    const float* __restrict__ mat_ambient,
    const float* __restrict__ mat_diffuse,
    const float* __restrict__ mat_specular,
    const float* __restrict__ camera_position,
    const int*   __restrict__ shininess_p,
    float*       __restrict__ colors,    // 3 floats per point
    int P)
{
    const int i = blockIdx.x * blockDim.x + threadIdx.x;
    if (i >= P) return;

    const float Lx = light_location[0], Ly = light_location[1], Lz = light_location[2];
    const float Cx = camera_position[0], Cy = camera_position[1], Cz = camera_position[2];
    const float amb0 = light_ambient[0] * mat_ambient[0];
    const float amb1 = light_ambient[1] * mat_ambient[1];
    const float amb2 = light_ambient[2] * mat_ambient[2];
    const float dif0 = light_diffuse[0] * mat_diffuse[0];
    const float dif1 = light_diffuse[1] * mat_diffuse[1];
    const float dif2 = light_diffuse[2] * mat_diffuse[2];
    const float spc0 = light_specular[0] * mat_specular[0];
    const float spc1 = light_specular[1] * mat_specular[1];
    const float spc2 = light_specular[2] * mat_specular[2];
    const int   shin = shininess_p[0];

    const size_t b = (size_t)i * 3;
    const float px = points[b],  py = points[b + 1],  pz = points[b + 2];
    const float nx = normals[b], ny = normals[b + 1], nz = normals[b + 2];

    // identical math/order to the verified per-pixel version
    float lx = Lx - px, ly = Ly - py, lz = Lz - pz;
    float ll = lx * lx + ly * ly + lz * lz;
    float li = (ll > 1e-12f) ? rsqrtf(ll) : 1e6f;
    lx *= li; ly *= li; lz *= li;

    const float cosv = nx * lx + ny * ly + nz * lz;

    float vx = Cx - px, vy = Cy - py, vz = Cz - pz;
    float vv = vx * vx + vy * vy + vz * vz;
    float vi = (vv > 1e-12f) ? rsqrtf(vv) : 1e6f;
    vx *= vi; vy *= vi; vz *= vi;

    const float c2 = 2.0f * cosv;
    const float rx = c2 * nx - lx;
    const float ry = c2 * ny - ly;
    const float rz = c2 * nz - lz;

    float alpha = fmaxf(vx * rx + vy * ry + vz * rz, 0.0f);
    if (!(cosv > 0.0f)) alpha = 0.0f;

    float sp = 1.0f, bb = alpha;
    int e = shin;
    while (e > 0) {
        if (e & 1) sp *= bb;
        bb *= bb;
        e >>= 1;
    }

    const float rc = fmaxf(cosv, 0.0f);
    colors[b]     = amb0 + dif0 * rc + spc0 * sp;
    colors[b + 1] = amb1 + dif1 * rc + spc1 * sp;
    colors[b + 2] = amb2 + dif2 * rc + spc2 * sp;
}

// ---------------------------------------------------------------------------
// Kernel 2: gather-and-blend, 2 pixels per thread.
// - streaming idx/dists: 4x int4 + 4x float4 nontemporal loads per thread
// - 16 gathers (12B each) issued up front for MLP
// - output: 3x float2 nontemporal stores (8B-aligned)
// ---------------------------------------------------------------------------
__global__ __launch_bounds__(256) void composite2_kernel(
    const int*   __restrict__ idx,
    const float* __restrict__ dists,
    const F3*    __restrict__ colors,
    float*       __restrict__ out,
    int n_pix)
{
    const int t  = blockIdx.x * blockDim.x + threadIdx.x;
    const int p0 = 2 * t;
    if (p0 >= n_pix) return;

    if (p0 + 1 < n_pix) {
        const i32x4* idxv = reinterpret_cast<const i32x4*>(idx + (size_t)p0 * K);
        const f32x4* dstv = reinterpret_cast<const f32x4*>(dists + (size_t)p0 * K);
        const i32x4 i0 = __builtin_nontemporal_load(idxv);
        const i32x4 i1 = __builtin_nontemporal_load(idxv + 1);
        const i32x4 i2 = __builtin_nontemporal_load(idxv + 2);
        const i32x4 i3 = __builtin_nontemporal_load(idxv + 3);
        const f32x4 d0 = __builtin_nontemporal_load(dstv);
        const f32x4 d1 = __builtin_nontemporal_load(dstv + 1);
        const f32x4 d2 = __builtin_nontemporal_load(dstv + 2);
        const f32x4 d3 = __builtin_nontemporal_load(dstv + 3);

        const int ik[2 * K] = {i0.x, i0.y, i0.z, i0.w, i1.x, i1.y, i1.z, i1.w,
                               i2.x, i2.y, i2.z, i2.w, i3.x, i3.y, i3.z, i3.w};
        const float dk[2 * K] = {d0.x, d0.y, d0.z, d0.w, d1.x, d1.y, d1.z, d1.w,
                                 d2.x, d2.y, d2.z, d2.w, d3.x, d3.y, d3.z, d3.w};

        // issue all 16 gathers first for max memory-level parallelism
        F3 ck[2 * K];
#pragma unroll
        for (int k = 0; k < 2 * K; ++k) {
            const int ii = (ik[k] < 0) ? 0 : ik[k];
            ck[k] = colors[ii];
        }

        float r[6];
#pragma unroll
        for (int px = 0; px < 2; ++px) {
            float wsum = 0.f, a0 = 0.f, a1 = 0.f, a2 = 0.f;
#pragma unroll
            for (int k = 0; k < K; ++k) {
                const int j = px * K + k;
                const float d = dk[j];
                const float m = (d != -1.0f) ? d : 0.0f;
                wsum += fabsf(m);
                a0 += m * ck[j].x;
                a1 += m * ck[j].y;
                a2 += m * ck[j].z;
            }
            const float winv = 1.0f / fmaxf(wsum, 1e-12f);
            r[3 * px]     = a0 * winv;
            r[3 * px + 1] = a1 * winv;
            r[3 * px + 2] = a2 * winv;
        }

        float* o = out + (size_t)p0 * 3;   // 24B per thread, 8B-aligned
        f32x2 s0; s0.x = r[0]; s0.y = r[1];
        f32x2 s1; s1.x = r[2]; s1.y = r[3];
        f32x2 s2; s2.x = r[4]; s2.y = r[5];
        __builtin_nontemporal_store(s0, reinterpret_cast<f32x2*>(o));
        __builtin_nontemporal_store(s1, reinterpret_cast<f32x2*>(o + 2));
        __builtin_nontemporal_store(s2, reinterpret_cast<f32x2*>(o + 4));
    } else {
        // tail: single pixel, scalar-safe path
        const i32x4* idxv = reinterpret_cast<const i32x4*>(idx + (size_t)p0 * K);
        const f32x4* dstv = reinterpret_cast<const f32x4*>(dists + (size_t)p0 * K);
        const i32x4 i0 = idxv[0], i1 = idxv[1];
        const f32x4 d0 = dstv[0], d1 = dstv[1];
        const int   ik[K] = {i0.x, i0.y, i0.z, i0.w, i1.x, i1.y, i1.z, i1.w};
        const float dk[K] = {d0.x, d0.y, d0.z, d0.w, d1.x, d1.y, d1.z, d1.w};
        float wsum = 0.f, a0 = 0.f, a1 = 0.f, a2 = 0.f;
#pragma unroll
        for (int k = 0; k < K; ++k) {
            const int ii = (ik[k] < 0) ? 0 : ik[k];
            const F3 c = colors[ii];
            const float d = dk[k];
            const float m = (d != -1.0f) ? d : 0.0f;
            wsum += fabsf(m);
            a0 += m * c.x; a1 += m * c.y; a2 += m * c.z;
        }
        const float winv = 1.0f / fmaxf(wsum, 1e-12f);
        float* o = out + (size_t)p0 * 3;
        o[0] = a0 * winv; o[1] = a1 * winv; o[2] = a2 * winv;
    }
}

// ---------------------------------------------------------------------------
// Fallback (workspace too small): previously-verified fused per-pixel kernel.
// ---------------------------------------------------------------------------
__global__ __launch_bounds__(256) void shading_compositor_fallback(
    const int*    __restrict__ idx,
    const float*  __restrict__ dists,
    const float*  __restrict__ points,
    const float*  __restrict__ normals,
    const float*  __restrict__ light_location,
    const float*  __restrict__ light_ambient,
    const float*  __restrict__ light_diffuse,
    const float*  __restrict__ light_specular,
    const float*  __restrict__ mat_ambient,
    const float*  __restrict__ mat_diffuse,
    const float*  __restrict__ mat_specular,
    const float*  __restrict__ camera_position,
    const int*    __restrict__ shininess_p,
    float*        __restrict__ out,
    int n_pix)
{
    const int p = blockIdx.x * blockDim.x + threadIdx.x;
    if (p >= n_pix) return;

    const float Lx = light_location[0], Ly = light_location[1], Lz = light_location[2];
    const float Cx = camera_position[0], Cy = camera_position[1], Cz = camera_position[2];
    const float amb0 = light_ambient[0] * mat_ambient[0];
    const float amb1 = light_ambient[1] * mat_ambient[1];
    const float amb2 = light_ambient[2] * mat_ambient[2];
    const float dif0 = light_diffuse[0] * mat_diffuse[0];
    const float dif1 = light_diffuse[1] * mat_diffuse[1];
    const float dif2 = light_diffuse[2] * mat_diffuse[2];
    const float spc0 = light_specular[0] * mat_specular[0];
    const float spc1 = light_specular[1] * mat_specular[1];
    const float spc2 = light_specular[2] * mat_specular[2];
    const int   shin = shininess_p[0];

    const int4*   idxv = reinterpret_cast<const int4*>(idx   + (size_t)p * K);
    const float4* dstv = reinterpret_cast<const float4*>(dists + (size_t)p * K);
    int4   i0 = idxv[0], i1 = idxv[1];
    float4 d0 = dstv[0], d1 = dstv[1];

    int   ik[K] = {i0.x, i0.y, i0.z, i0.w, i1.x, i1.y, i1.z, i1.w};
    float dk[K] = {d0.x, d0.y, d0.z, d0.w, d1.x, d1.y, d1.z, d1.w};

    float w[K];
    float wsum = 0.f;
#pragma unroll
    for (int k = 0; k < K; ++k) {
        float d = dk[k];
        float m = (d != -1.0f) ? d : 0.0f;
        w[k] = m;
        wsum += fabsf(m);
    }
    const float winv = 1.0f / fmaxf(wsum, 1e-12f);

    float acc0 = 0.f, acc1 = 0.f, acc2 = 0.f;

#pragma unroll
    for (int k = 0; k < K; ++k) {
        const int ii = (ik[k] < 0) ? 0 : ik[k];
        const size_t base = (size_t)ii * 3;
        const float px = points[base],  py = points[base + 1],  pz = points[base + 2];
        const float nx = normals[base], ny = normals[base + 1], nz = normals[base + 2];

        float lx = Lx - px, ly = Ly - py, lz = Lz - pz;
        float ll = lx * lx + ly * ly + lz * lz;
        float li = (ll > 1e-12f) ? rsqrtf(ll) : 1e6f;
        lx *= li; ly *= li; lz *= li;

        const float cosv = nx * lx + ny * ly + nz * lz;

        float vx = Cx - px, vy = Cy - py, vz = Cz - pz;
        float vv = vx * vx + vy * vy + vz * vz;
        float vi = (vv > 1e-12f) ? rsqrtf(vv) : 1e6f;
        vx *= vi; vy *= vi; vz *= vi;

        const float c2 = 2.0f * cosv;
        const float rx = c2 * nx - lx;
        const float ry = c2 * ny - ly;
        const float rz = c2 * nz - lz;

        float alpha = fmaxf(vx * rx + vy * ry + vz * rz, 0.0f);
        if (!(cosv > 0.0f)) alpha = 0.0f;

        float sp = 1.0f, bb = alpha;
        int e = shin;
        while (e > 0) {
            if (e & 1) sp *= bb;
            bb *= bb;
            e >>= 1;
        }

        const float rc = fmaxf(cosv, 0.0f);
        const float wk = w[k];
        acc0 += wk * (amb0 + dif0 * rc + spc0 * sp);
        acc1 += wk * (amb1 + dif1 * rc + spc1 * sp);
        acc2 += wk * (amb2 + dif2 * rc + spc2 * sp);
    }

    float* o = out + (size_t)p * 3;
    o[0] = acc0 * winv;
    o[1] = acc1 * winv;
    o[2] = acc2 * winv;
}

extern "C" void kernel_launch(void* const* d_in, const int* in_sizes, int n_in,
                              void* d_out, int out_size, void* d_ws, size_t ws_size,
                              hipStream_t stream) {
    const int*   idx             = (const int*)d_in[0];
    const float* dists           = (const float*)d_in[1];
    const float* points          = (const float*)d_in[2];
    const float* normals         = (const float*)d_in[3];
    const float* light_location  = (const float*)d_in[4];
    const float* light_ambient   = (const float*)d_in[5];
    const float* light_diffuse   = (const float*)d_in[6];
    const float* light_specular  = (const float*)d_in[7];
    const float* mat_ambient     = (const float*)d_in[8];
    const float* mat_diffuse     = (const float*)d_in[9];
    const float* mat_specular    = (const float*)d_in[10];
    const float* camera_position = (const float*)d_in[11];
    const int*   shininess       = (const int*)d_in[12];
    float*       out             = (float*)d_out;

    const int n_pix = in_sizes[0] / K;       // N*H*W
    const int P     = in_sizes[2] / 3;       // number of points

    const int block = 256;

    const size_t need = (size_t)P * 3 * sizeof(float);
    if (ws_size >= need) {
        float* colors = (float*)d_ws;
        shade_points_kernel<<<(P + block - 1) / block, block, 0, stream>>>(
            points, normals, light_location, light_ambient, light_diffuse,
            light_specular, mat_ambient, mat_diffuse, mat_specular,
            camera_position, shininess, colors, P);
        const int n_thr  = (n_pix + 1) / 2;
        const int grid2  = (n_thr + block - 1) / block;
        composite2_kernel<<<grid2, block, 0, stream>>>(
            idx, dists, (const F3*)colors, out, n_pix);
    } else {
        const int grid = (n_pix + block - 1) / block;
        shading_compositor_fallback<<<grid, block, 0, stream>>>(
            idx, dists, points, normals, light_location, light_ambient,
            light_diffuse, light_specular, mat_ambient, mat_diffuse,
            mat_specular, camera_position, shininess, out, n_pix);
    }
}